// Round 6
// baseline (709.386 us; speedup 1.0000x reference)
//
#include <hip/hip_runtime.h>
#include <hip/hip_cooperative_groups.h>
#include <cstddef>

namespace cg = cooperative_groups;

#define B_ 32
#define C_ 32
#define L_ 16384
#define H_ 4
#define NB_ 3
#define DOUT_ 10
#define SEG_ 512
#define S_ (L_/SEG_)            // 32 segments per (b,head)
#define NSU (B_*H_*S_)          // 4096 stats units
#define NPAIR (B_*(L_/256)/2)   // 1024 pairs of 256-pos tiles
#define AST 40                  // A_lds row stride (halfs): 80 B/row, 16B-aligned frags

// LDS layout (single 27008 B arena; stats tile aliases Ash)
#define OFF_SM    16384
#define OFF_B1    20480
#define OFF_B2    23040
#define OFF_SB1   25600
#define OFF_SB2   25728
#define OFF_KV    25856
#define OFF_POOL  26880
#define LDS_BYTES 27008

typedef _Float16 f16_t;
typedef _Float16 f16x2 __attribute__((ext_vector_type(2)));
typedef _Float16 f16x8 __attribute__((ext_vector_type(8)));
typedef float    f32x4 __attribute__((ext_vector_type(4)));

// Branch-free gelu via Abramowitz-Stegun 7.1.26 erf approximation (|eps|<=1.5e-7).
__device__ __forceinline__ float gelu_f(float x){
    const float z  = fabsf(x) * 0.70710678118654752440f;
    const float t  = __builtin_amdgcn_rcpf(fmaf(0.3275911f, z, 1.0f));
    const float e  = __expf(-z * z);
    float p = fmaf(t, 1.061405429f, -1.453152027f);
    p = fmaf(t, p, 1.421413741f);
    p = fmaf(t, p, -0.284496736f);
    p = fmaf(t, p, 0.254829592f);
    const float erfz = 1.0f - p * t * e;
    const float phi  = fmaf(copysignf(erfz, x), 0.5f, 0.5f);
    return x * phi;
}

#define RED_MAX32(v) do{ v = fmaxf(v, __shfl_xor(v,1));  v = fmaxf(v, __shfl_xor(v,2)); \
                         v = fmaxf(v, __shfl_xor(v,4));  v = fmaxf(v, __shfl_xor(v,8)); \
                         v = fmaxf(v, __shfl_xor(v,16)); }while(0)
#define RED_SUM32(v) do{ v += __shfl_xor(v,1);  v += __shfl_xor(v,2); \
                         v += __shfl_xor(v,4);  v += __shfl_xor(v,8); \
                         v += __shfl_xor(v,16); }while(0)

// ---- block phase: per-position attention (fp32) + FC1/FC2 via f16 MFMA ----
// Barrier inventory per pair (R5-verified: Ash rows are WAVE-PRIVATE, so
// attn-write->FC1-frag-read and FC1-writeback->FC2-read need NO barrier --
// same-wave LDS ops execute in order): only 2 __syncthreads per pair, both
// for kvsh (cross-wave).
template<bool LASTL>
__device__ __forceinline__
void block_phase(char* LB, const float* __restrict__ src, float* __restrict__ hbuf,
                 const float* __restrict__ part,
                 const float* __restrict__ W1, const float* __restrict__ b1w,
                 const float* __restrict__ W2, const float* __restrict__ b2w,
                 float* __restrict__ pooled,
                 const int tid, const int wg, const int nwg)
{
    f16_t* Ash   = (f16_t*)LB;
    f16_t* Bs1   = (f16_t*)(LB + OFF_B1);
    f16_t* Bs2   = (f16_t*)(LB + OFF_B2);
    float* sb1   = (float*)(LB + OFF_SB1);
    float* sb2   = (float*)(LB + OFF_SB2);
    float* kvsh  = (float*)(LB + OFF_KV);
    float* poolS = (float*)(LB + OFF_POOL);

    // stage weights once per layer (visible after the first in-loop barrier)
    for (int i = tid; i < 1024; i += 256){
        const int k = i >> 5, n = i & 31;
        Bs1[n*AST + k] = (f16_t)W1[i];
        Bs2[n*AST + k] = (f16_t)W2[i];
    }
    if (tid < 32){ sb1[tid] = b1w[tid]; sb2[tid] = b2w[tid]; if (LASTL) poolS[tid] = 0.0f; }

    const int wv = tid >> 6, lane = tid & 63, lr = lane & 15, lk = lane >> 4;
    const f32x4 zero = {0.f, 0.f, 0.f, 0.f};

    for (int pr = wg; pr < NPAIR; pr += nwg){
        const int t0 = pr * 2;             // tiles t0, t0+1 share the same batch
        const int b  = t0 >> 6;
        const int l0 = (t0 & 63) << 8;
        const size_t base = (size_t)b * ((size_t)C_*L_);

        float h0[32], h1[32];
        #pragma unroll
        for (int c = 0; c < 32; c++) h0[c] = src[base + (size_t)c*L_ + l0 + tid];
        #pragma unroll
        for (int c = 0; c < 32; c++) h1[c] = src[base + (size_t)c*L_ + l0 + 256 + tid];

        __syncthreads();   // previous pair's kvsh reads complete

        {   // merge segment partials -> kvsh (L2-hot; hides the h loads above)
            const int hh = tid >> 6, tt = tid & 63, dd = tt >> 3;
            const float* pp = part + (size_t)(b*H_ + hh) * S_ * 80;
            float M = -INFINITY;
            for (int s2 = 0; s2 < S_; s2++) M = fmaxf(M, pp[s2*80 + dd]);
            float ssum = 0.0f, kvs = 0.0f;
            for (int s2 = 0; s2 < S_; s2++){
                const float sc = __expf(pp[s2*80 + dd] - M);
                ssum = fmaf(pp[s2*80 + 8  + dd], sc, ssum);
                kvs  = fmaf(pp[s2*80 + 16 + tt], sc, kvs);
            }
            kvsh[tid] = kvs / ssum;
        }
        __syncthreads();   // kvsh (+ weights on first iter) visible

        auto do_tile = [&](const float (&hv)[32], const int lofs){
            // attention (fp32, per-thread)
            float attn[32];
            #pragma unroll
            for (int hd2 = 0; hd2 < 4; hd2++){
                float mq = hv[hd2*8];
                #pragma unroll
                for (int d2 = 1; d2 < 8; d2++) mq = fmaxf(mq, hv[hd2*8 + d2]);
                float es[8]; float qs = 0.f;
                #pragma unroll
                for (int d2 = 0; d2 < 8; d2++){ es[d2] = __expf(hv[hd2*8 + d2] - mq); qs += es[d2]; }
                const float inv = __builtin_amdgcn_rcpf(qs);
                #pragma unroll
                for (int e = 0; e < 8; e++){
                    float acc = 0.f;
                    #pragma unroll
                    for (int d2 = 0; d2 < 8; d2++) acc += es[d2] * kvsh[hd2*64 + d2*8 + e];
                    attn[hd2*8 + e] = acc * inv;
                }
            }
            #pragma unroll
            for (int k2 = 0; k2 < 32; k2 += 2){
                f16x2 pv = { (f16_t)attn[k2], (f16_t)attn[k2+1] };
                *(f16x2*)&Ash[tid*AST + k2] = pv;
            }
            // FC1 (wave-private Ash rows: no barrier)
            f16x8 a[4], bw[2];
            f32x4 d[8];
            #pragma unroll
            for (int mt = 0; mt < 4; mt++)
                a[mt] = *(const f16x8*)&Ash[(wv*64 + mt*16 + lr)*AST + lk*8];
            #pragma unroll
            for (int nt = 0; nt < 2; nt++)
                bw[nt] = *(const f16x8*)&Bs1[(nt*16 + lr)*AST + lk*8];
            #pragma unroll
            for (int nt = 0; nt < 2; nt++)
                #pragma unroll
                for (int mt = 0; mt < 4; mt++)
                    d[nt*4+mt] = __builtin_amdgcn_mfma_f32_16x16x32_f16(a[mt], bw[nt], zero, 0, 0, 0);
            // bias + gelu + writeback as A2 (wave-private rows)
            #pragma unroll
            for (int nt = 0; nt < 2; nt++){
                const float bias = sb1[nt*16 + lr];
                #pragma unroll
                for (int mt = 0; mt < 4; mt++)
                    #pragma unroll
                    for (int r = 0; r < 4; r++){
                        const float v = gelu_f(d[nt*4+mt][r] + bias);
                        Ash[(wv*64 + mt*16 + lk*4 + r)*AST + (nt*16 + lr)] = (f16_t)v;
                    }
            }
            // FC2
            #pragma unroll
            for (int mt = 0; mt < 4; mt++)
                a[mt] = *(const f16x8*)&Ash[(wv*64 + mt*16 + lr)*AST + lk*8];
            #pragma unroll
            for (int nt = 0; nt < 2; nt++)
                bw[nt] = *(const f16x8*)&Bs2[(nt*16 + lr)*AST + lk*8];
            #pragma unroll
            for (int nt = 0; nt < 2; nt++)
                #pragma unroll
                for (int mt = 0; mt < 4; mt++)
                    d[nt*4+mt] = __builtin_amdgcn_mfma_f32_16x16x32_f16(a[mt], bw[nt], zero, 0, 0, 0);
            #pragma unroll
            for (int nt = 0; nt < 2; nt++){
                const float bias = sb2[nt*16 + lr];
                #pragma unroll
                for (int mt = 0; mt < 4; mt++)
                    #pragma unroll
                    for (int r = 0; r < 4; r++)
                        d[nt*4+mt][r] = gelu_f(d[nt*4+mt][r] + bias);
            }
            if (!LASTL){
                // lane owns 4 consecutive positions of channel nt*16+lr: full 64-B lines
                #pragma unroll
                for (int nt = 0; nt < 2; nt++)
                    #pragma unroll
                    for (int mt = 0; mt < 4; mt++)
                        *(f32x4*)&hbuf[base + (size_t)(nt*16 + lr)*L_
                                       + lofs + wv*64 + mt*16 + lk*4] = d[nt*4+mt];
            } else {
                #pragma unroll
                for (int nt = 0; nt < 2; nt++){
                    float ps = 0.f;
                    #pragma unroll
                    for (int mt = 0; mt < 4; mt++)
                        ps += d[nt*4+mt][0] + d[nt*4+mt][1] + d[nt*4+mt][2] + d[nt*4+mt][3];
                    atomicAdd(&poolS[nt*16 + lr], ps);
                }
            }
        };

        do_tile(h0, l0);
        do_tile(h1, l0 + 256);

        if (LASTL){
            // flush per pair: pairs on this WG have different b
            __syncthreads();
            if (tid < 32){ atomicAdd(&pooled[b*32 + tid], poolS[tid]); poolS[tid] = 0.0f; }
        }
    }
}

// ---- the whole network in one cooperative launch ----
// Rationale (R5 post-mortem): sum(kernel durs) ~220 us vs dur_us ~300 us --
// ~80 us of inter-dispatch overhead across ~11 dependent launches. 6 grid.syncs
// replace all internal boundaries. Grid sized by occupancy query (<=1024 WGs,
// 27 KB LDS -> 5 WG/CU co-resident) so cooperative validation cannot fail.
// waves_per_eu(3,4): R1/R2-proven spill-free config (min>=5 crushes the ~75-reg
// live set to 40-48 and spills 30-55 MB/dispatch).
__global__ __launch_bounds__(256)
__attribute__((amdgpu_waves_per_eu(3, 4)))
void fused_all(const float* __restrict__ x, float* __restrict__ hbuf,
               float* __restrict__ part, float* __restrict__ pooled,
               const float* __restrict__ fW1, const float* __restrict__ fb1,
               const float* __restrict__ fW2, const float* __restrict__ fb2,
               const float* __restrict__ Wh,  const float* __restrict__ bh,
               const float* __restrict__ gam, const float* __restrict__ bet,
               const float* __restrict__ mean,const float* __restrict__ var,
               const float* __restrict__ Wf,  const float* __restrict__ bf,
               float* __restrict__ out)
{
    __shared__ __align__(16) char LB[LDS_BYTES];
    const int tid = threadIdx.x;
    const int wg  = blockIdx.x;
    const int nwg = gridDim.x;
    cg::grid_group grid = cg::this_grid();

    // zero pooled (consumed in layer 2, >=5 syncs later)
    if (wg == 0) for (int i = tid; i < B_*C_; i += 256) pooled[i] = 0.0f;

    #pragma unroll 1
    for (int layer = 0; layer < NB_; ++layer){
        const float* src = layer ? hbuf : x;

        // ======== stats phase: per (b,head,seg) max/sumexp/kv partials ========
        {
            float* tile = (float*)LB;               // [8][512] = 16 KB (aliases Ash)
            float* sm   = (float*)(LB + OFF_SM);
            const int dd = tid >> 5, j = tid & 31;
            for (int u = wg; u < NSU; u += nwg){
                const int seg = u & 31, hd = (u >> 5) & 3, b = u >> 7;
                const float* hb = src + (size_t)b*((size_t)C_*L_)
                                      + (size_t)(hd*8)*L_ + (size_t)seg*SEG_;
                for (int f = tid; f < 8*SEG_/4; f += 256){
                    const int row = f >> 7, c4 = (f & 127) << 2;
                    *(f32x4*)&tile[row*SEG_ + c4] = *(const f32x4*)&hb[(size_t)row*L_ + c4];
                }
                __syncthreads();
                float m = -INFINITY;
                #pragma unroll
                for (int i = 0; i < SEG_/32; i++) m = fmaxf(m, tile[dd*SEG_ + j + 32*i]);
                RED_MAX32(m);
                if (j == 0) sm[dd] = m;
                float s = 0.0f, kv[8];
                #pragma unroll
                for (int e = 0; e < 8; e++) kv[e] = 0.0f;
                #pragma unroll
                for (int i = 0; i < SEG_/32; i++){
                    const int k = j + 32*i;
                    const float ek = __expf(tile[dd*SEG_ + k] - m);
                    s += ek;
                    #pragma unroll
                    for (int e = 0; e < 8; e++) kv[e] = fmaf(ek, tile[e*SEG_ + k], kv[e]);
                }
                RED_SUM32(s);
                #pragma unroll
                for (int e = 0; e < 8; e++){ RED_SUM32(kv[e]); }
                __syncthreads();   // all tile reads done; sm visible; guards reuse
                float* po = part + (size_t)u * 80;
                if (j == 0){
                    po[8 + dd] = s;
                    #pragma unroll
                    for (int e = 0; e < 8; e++) po[16 + dd*8 + e] = kv[e];
                }
                if (tid < 8) po[tid] = sm[tid];
            }
        }
        grid.sync();

        // ======== block phase ========
        if (layer < NB_-1)
            block_phase<false>(LB, src, hbuf, part, fW1 + layer*C_*C_, fb1 + layer*C_,
                               fW2 + layer*C_*C_, fb2 + layer*C_, pooled, tid, wg, nwg);
        else
            block_phase<true >(LB, src, hbuf, part, fW1 + layer*C_*C_, fb1 + layer*C_,
                               fW2 + layer*C_*C_, fb2 + layer*C_, pooled, tid, wg, nwg);
        grid.sync();
    }

    // ======== head: pooled/L -> Wh+bh -> BN(eval) -> gelu -> Wf+bf ========
    if (wg == 0){
        float* y2 = (float*)LB;    // 4 KB scratch, Ash dead
        const float invL = 1.0f / (float)L_;
        for (int i = tid; i < B_*C_; i += 256){
            const int bb = i >> 5, cc = i & 31;
            float acc = bh[cc];
            #pragma unroll
            for (int d2 = 0; d2 < 32; d2++)
                acc += (pooled[bb*32 + d2] * invL) * Wh[d2*32 + cc];
            acc = (acc - mean[cc]) * rsqrtf(var[cc] + 1e-5f) * gam[cc] + bet[cc];
            y2[i] = gelu_f(acc);
        }
        __syncthreads();
        for (int i = tid; i < B_*DOUT_; i += 256){
            const int b2 = i / DOUT_, jj = i % DOUT_;
            float r = bf[jj];
            #pragma unroll
            for (int c2 = 0; c2 < 32; c2++) r += y2[b2*32 + c2] * Wf[c2*DOUT_ + jj];
            out[i] = r;
        }
    }
}

extern "C" void kernel_launch(void* const* d_in, const int* in_sizes, int n_in,
                              void* d_out, int out_size, void* d_ws, size_t ws_size,
                              hipStream_t stream){
    (void)in_sizes; (void)n_in; (void)out_size; (void)ws_size;
    const float* x    = (const float*)d_in[0];
    const float* fW1  = (const float*)d_in[1];
    const float* fb1  = (const float*)d_in[2];
    const float* fW2  = (const float*)d_in[3];
    const float* fb2  = (const float*)d_in[4];
    const float* Wh   = (const float*)d_in[5];
    const float* bh   = (const float*)d_in[6];
    const float* gam  = (const float*)d_in[7];
    const float* bet  = (const float*)d_in[8];
    const float* mean = (const float*)d_in[9];
    const float* var  = (const float*)d_in[10];
    const float* Wf   = (const float*)d_in[11];
    const float* bf   = (const float*)d_in[12];
    float* out = (float*)d_out;

    float* hbuf   = (float*)d_ws;                          // B*C*L floats (64 MB)
    float* part   = hbuf + (size_t)B_*C_*L_;               // NSU*80 (~1.3 MB)
    float* pooled = part + (size_t)NSU*80;                 // B*C

    // one-time: grid = min(1024, co-residency limit) -- cooperative launch
    // requires all WGs resident; query-driven grid cannot over-subscribe.
    static int g_grid = 0;
    if (g_grid == 0){
        int nb = 0;
        if (hipOccupancyMaxActiveBlocksPerMultiprocessor(
                &nb, reinterpret_cast<const void*>(&fused_all), 256, 0) != hipSuccess
            || nb <= 0) nb = 3;
        int ncu = 256;
        int dev = 0;
        if (hipGetDevice(&dev) == hipSuccess){
            hipDeviceProp_t prop;
            if (hipGetDeviceProperties(&prop, dev) == hipSuccess && prop.multiProcessorCount > 0)
                ncu = prop.multiProcessorCount;
        }
        long g = (long)nb * ncu;
        if (g > 1024) g = 1024;
        if (g < 128)  g = 128;
        g_grid = (int)g;
    }

    void* args[] = { (void*)&x, (void*)&hbuf, (void*)&part, (void*)&pooled,
                     (void*)&fW1, (void*)&fb1, (void*)&fW2, (void*)&fb2,
                     (void*)&Wh, (void*)&bh, (void*)&gam, (void*)&bet,
                     (void*)&mean, (void*)&var, (void*)&Wf, (void*)&bf,
                     (void*)&out };
    hipLaunchCooperativeKernel(reinterpret_cast<const void*>(&fused_all),
                               dim3(g_grid), dim3(256), args, 0, stream);
}

// Round 7
// 298.212 us; speedup vs baseline: 2.3788x; 2.3788x over previous
//
#include <hip/hip_runtime.h>
#include <cstddef>

#define B_ 32
#define C_ 32
#define L_ 16384
#define H_ 4
#define DH_ 8
#define NB_ 3
#define DOUT_ 10
#define SEG_ 512
#define S_ (L_/SEG_)   // 32 segments per (b,head)

#define TILE 256
#define AST  40    // A_lds row stride (halfs): 80 B/row -> 16B-aligned b128 frag reads

typedef _Float16 f16_t;
typedef _Float16 f16x2 __attribute__((ext_vector_type(2)));
typedef _Float16 f16x8 __attribute__((ext_vector_type(8)));
typedef float    f32x4 __attribute__((ext_vector_type(4)));

// Branch-free gelu via Abramowitz-Stegun 7.1.26 erf approximation (|eps|<=1.5e-7).
__device__ __forceinline__ float gelu_f(float x){
    const float z  = fabsf(x) * 0.70710678118654752440f;
    const float t  = __builtin_amdgcn_rcpf(fmaf(0.3275911f, z, 1.0f));
    const float e  = __expf(-z * z);
    float p = fmaf(t, 1.061405429f, -1.453152027f);
    p = fmaf(t, p, 1.421413741f);
    p = fmaf(t, p, -0.284496736f);
    p = fmaf(t, p, 0.254829592f);
    const float erfz = 1.0f - p * t * e;
    const float phi  = fmaf(copysignf(erfz, x), 0.5f, 0.5f);
    return x * phi;
}

#define RED_MAX32(v) do{ v = fmaxf(v, __shfl_xor(v,1));  v = fmaxf(v, __shfl_xor(v,2)); \
                         v = fmaxf(v, __shfl_xor(v,4));  v = fmaxf(v, __shfl_xor(v,8)); \
                         v = fmaxf(v, __shfl_xor(v,16)); }while(0)
#define RED_SUM32(v) do{ v += __shfl_xor(v,1);  v += __shfl_xor(v,2); \
                         v += __shfl_xor(v,4);  v += __shfl_xor(v,8); \
                         v += __shfl_xor(v,16); }while(0)

// ---- stats: per (b, head, seg) partial max / sumexp / kv over a 512-pos segment ----
// 4096 independent WGs, ~13 us at ~4.9 TB/s effective (L3-assisted): near floor.
// R3 (epilogue-fusion) and R6 (cooperative grid-stride) both regressed this.
__global__ __launch_bounds__(256) void stats_kernel(const float* __restrict__ h,
                                                    float* __restrict__ part){
    const int seg = blockIdx.x;
    const int hd  = blockIdx.y;
    const int b   = blockIdx.z;
    const int t   = threadIdx.x;
    const int d   = t >> 5;   // 0..7  (feature within head); wave-half owns one d
    const int j   = t & 31;   // 0..31 (position lane)

    __shared__ float tile[8][SEG_];   // 16 KB
    __shared__ float sm[8];

    const float* hb = h + (size_t)b * ((size_t)C_*L_) + (size_t)(hd*DH_)*L_ + (size_t)seg*SEG_;

    for (int f = t; f < 8*SEG_/4; f += 256){
        const int row = f >> 7;
        const int c4  = (f & 127) << 2;
        *(f32x4*)&tile[row][c4] = *(const f32x4*)&hb[(size_t)row*L_ + c4];
    }
    __syncthreads();

    float m = -INFINITY;
    #pragma unroll
    for (int i = 0; i < SEG_/32; i++) m = fmaxf(m, tile[d][j + 32*i]);
    RED_MAX32(m);
    if (j == 0) sm[d] = m;
    const float m_d = m;

    float s = 0.0f;
    float kv[8];
    #pragma unroll
    for (int e = 0; e < 8; e++) kv[e] = 0.0f;
    #pragma unroll
    for (int i = 0; i < SEG_/32; i++){
        const int k = j + 32*i;
        const float ek = __expf(tile[d][k] - m_d);
        s += ek;
        #pragma unroll
        for (int e = 0; e < 8; e++) kv[e] = fmaf(ek, tile[e][k], kv[e]);
    }
    RED_SUM32(s);
    #pragma unroll
    for (int e = 0; e < 8; e++){ RED_SUM32(kv[e]); }
    __syncthreads();

    float* po = part + (size_t)((b*H_ + hd)*S_ + seg) * 80;
    if (j == 0){
        po[8 + d] = s;
        #pragma unroll
        for (int e = 0; e < 8; e++) po[16 + d*8 + e] = kv[e];
    }
    if (t < 8) po[t] = sm[t];
}

// ---- merge segment partials -> normalized kvn[b][head][d][e] = kv/s ----
// Standalone again (R6 lesson: dispatch-count is NOT the lever; the fused merge
// added +2.8 us to every block WG's critical path for no end-to-end gain).
__global__ __launch_bounds__(256) void merge_kernel(const float* __restrict__ part,
                                                    float* __restrict__ kvn){
    const int bh = blockIdx.x;              // 0..B*H-1
    const int t  = threadIdx.x & 63;        // (d,e)
    const int g  = threadIdx.x >> 6;        // 0..3 segment group
    const int d  = t >> 3;
    const float* p = part + (size_t)bh * S_ * 80;
    __shared__ float r1[4][64], r2[4][64];

    float M = -INFINITY;
    for (int s2 = g; s2 < S_; s2 += 4) M = fmaxf(M, p[s2*80 + d]);
    r1[g][t] = M;
    __syncthreads();
    M = fmaxf(fmaxf(r1[0][t], r1[1][t]), fmaxf(r1[2][t], r1[3][t]));
    __syncthreads();

    float ssum = 0.0f, kvsum = 0.0f;
    for (int s2 = g; s2 < S_; s2 += 4){
        const float sc = __expf(p[s2*80 + d] - M);
        ssum  += p[s2*80 + 8  + d] * sc;
        kvsum += p[s2*80 + 16 + t] * sc;
    }
    r1[g][t] = ssum; r2[g][t] = kvsum;
    __syncthreads();
    if (g == 0){
        ssum  = r1[0][t]+r1[1][t]+r1[2][t]+r1[3][t];
        kvsum = r2[0][t]+r2[1][t]+r2[2][t]+r2[3][t];
        kvn[(size_t)bh*64 + t] = kvsum / ssum;
    }
}

// ---- per-position attention (fp32) + FC1/FC2 via f16 MFMA ----
// ONE barrier total (two in LAST). Proven facts used:
//  * Ash rows are WAVE-PRIVATE: attn-write -> FC1-frag-read and FC1-writeback ->
//    FC2-read need no __syncthreads (R5-verified on HW). The single barrier
//    orders the cross-wave weight staging only.
//  * D-register direct f32x4 stores (R5-verified): lane owns 4 consecutive
//    positions x 1 channel; a wave's 16 stores per (nt,mt) are full 64-B lines.
//    Kills the O16 transpose + its 4 barriers + LDS round-trip.
//  * kv read as wave-uniform scalar loads from global kvn (R0 structure, 41 us).
//  * waves_per_eu(3,4): only spill-free config (R1/R2: min>=5 crushes the
//    ~75-reg live set to 40-48 VGPRs and spills 30-55 MB/dispatch).
// MFMA layouts (m89/m91-verified): A-frag lane holds A[m=lane&15][k=(lane>>4)*8+j];
// B-frag B[k][n=lane&15] (stored Bsh[n][k]); C/D col=lane&15, row=(lane>>4)*4+reg.
template<bool LAST>
__global__ __launch_bounds__(256)
__attribute__((amdgpu_waves_per_eu(3, 4)))
void block_kernel(const float* hin,
                  float* hout,
                  const float* __restrict__ kvn,
                  const float* __restrict__ W1,
                  const float* __restrict__ b1,
                  const float* __restrict__ W2,
                  const float* __restrict__ b2,
                  float* __restrict__ pooled){
    __shared__ __align__(16) f16_t Ash[TILE*AST];  // 20480 B
    __shared__ f16_t Bsh1[32*AST];                 // 2560 B: W1 as [n][k]
    __shared__ f16_t Bsh2[32*AST];                 // 2560 B
    __shared__ float sb1[32], sb2[32];
    __shared__ float pool[32];

    const int tid = threadIdx.x;
    const int b   = blockIdx.y;
    const int l0  = blockIdx.x * TILE;
    const int l   = l0 + tid;
    const size_t base = (size_t)b * ((size_t)C_*L_);
    const float* kv = kvn + (size_t)b * (H_*DH_*DH_);

    // prologue: h loads in flight; weight staging hides them
    float h[32];
    #pragma unroll
    for (int c = 0; c < 32; c++) h[c] = hin[base + (size_t)c*L_ + l];

    for (int i = tid; i < 1024; i += 256){
        const int k = i >> 5, n = i & 31;
        Bsh1[n*AST + k] = (f16_t)W1[i];
        Bsh2[n*AST + k] = (f16_t)W2[i];
    }
    if (tid < 32){ sb1[tid] = b1[tid]; sb2[tid] = b2[tid]; }
    if (LAST && tid < 32) pool[tid] = 0.0f;

    // ---- phase 1: per-thread fp32 attention (kv reads are wave-uniform -> SMEM)
    float attn[32];
    #pragma unroll
    for (int hh = 0; hh < 4; hh++){
        float mq = h[hh*8];
        #pragma unroll
        for (int d2 = 1; d2 < 8; d2++) mq = fmaxf(mq, h[hh*8 + d2]);
        float es[8]; float qs = 0.f;
        #pragma unroll
        for (int d2 = 0; d2 < 8; d2++){ es[d2] = __expf(h[hh*8 + d2] - mq); qs += es[d2]; }
        const float inv = __builtin_amdgcn_rcpf(qs);
        #pragma unroll
        for (int e = 0; e < 8; e++){
            float a = 0.f;
            #pragma unroll
            for (int d2 = 0; d2 < 8; d2++) a += es[d2] * kv[hh*64 + d2*8 + e];
            attn[hh*8 + e] = a * inv;
        }
    }

    // attn -> f16 A matrix in LDS (wave-private rows)
    #pragma unroll
    for (int k2 = 0; k2 < 32; k2 += 2){
        f16x2 pr = { (f16_t)attn[k2], (f16_t)attn[k2+1] };
        *(f16x2*)&Ash[tid*AST + k2] = pr;
    }
    __syncthreads();   // the ONLY barrier: weights (+ LAST pool init) visible

    // ---- phase 2: MFMA FCs (no further barriers; all Ash traffic wave-private)
    const int wv   = tid >> 6;
    const int lane = tid & 63;
    const int lr   = lane & 15;
    const int lk   = lane >> 4;
    const f32x4 zero = {0.f, 0.f, 0.f, 0.f};

    f16x8 a[4], bw[2];
    f32x4 d[8];

    // FC1
    #pragma unroll
    for (int mt = 0; mt < 4; mt++)
        a[mt] = *(const f16x8*)&Ash[(wv*64 + mt*16 + lr)*AST + lk*8];
    #pragma unroll
    for (int nt = 0; nt < 2; nt++)
        bw[nt] = *(const f16x8*)&Bsh1[(nt*16 + lr)*AST + lk*8];
    #pragma unroll
    for (int nt = 0; nt < 2; nt++)
        #pragma unroll
        for (int mt = 0; mt < 4; mt++)
            d[nt*4+mt] = __builtin_amdgcn_mfma_f32_16x16x32_f16(a[mt], bw[nt], zero, 0, 0, 0);

    // bias + gelu + writeback as A2 (wave-private rows; no barrier)
    #pragma unroll
    for (int nt = 0; nt < 2; nt++){
        const float bias = sb1[nt*16 + lr];
        #pragma unroll
        for (int mt = 0; mt < 4; mt++)
            #pragma unroll
            for (int r = 0; r < 4; r++){
                const float v = gelu_f(d[nt*4+mt][r] + bias);
                Ash[(wv*64 + mt*16 + lk*4 + r)*AST + (nt*16 + lr)] = (f16_t)v;
            }
    }

    // FC2
    #pragma unroll
    for (int mt = 0; mt < 4; mt++)
        a[mt] = *(const f16x8*)&Ash[(wv*64 + mt*16 + lr)*AST + lk*8];
    #pragma unroll
    for (int nt = 0; nt < 2; nt++)
        bw[nt] = *(const f16x8*)&Bsh2[(nt*16 + lr)*AST + lk*8];
    #pragma unroll
    for (int nt = 0; nt < 2; nt++)
        #pragma unroll
        for (int mt = 0; mt < 4; mt++)
            d[nt*4+mt] = __builtin_amdgcn_mfma_f32_16x16x32_f16(a[mt], bw[nt], zero, 0, 0, 0);

    // bias + gelu on D (fp32)
    #pragma unroll
    for (int nt = 0; nt < 2; nt++){
        const float bias = sb2[nt*16 + lr];
        #pragma unroll
        for (int mt = 0; mt < 4; mt++)
            #pragma unroll
            for (int r = 0; r < 4; r++)
                d[nt*4+mt][r] = gelu_f(d[nt*4+mt][r] + bias);
    }

    if (!LAST){
        // direct store: lane owns 4 consecutive positions of channel nt*16+lr
        #pragma unroll
        for (int nt = 0; nt < 2; nt++)
            #pragma unroll
            for (int mt = 0; mt < 4; mt++)
                *(f32x4*)&hout[base + (size_t)(nt*16 + lr)*L_
                               + l0 + wv*64 + mt*16 + lk*4] = d[nt*4+mt];
    } else {
        #pragma unroll
        for (int nt = 0; nt < 2; nt++){
            float ps = 0.f;
            #pragma unroll
            for (int mt = 0; mt < 4; mt++)
                ps += d[nt*4+mt][0] + d[nt*4+mt][1] + d[nt*4+mt][2] + d[nt*4+mt][3];
            atomicAdd(&pool[nt*16 + lr], ps);
        }
        __syncthreads();
        if (tid < 32) atomicAdd(&pooled[b*32 + tid], pool[tid]);
    }
}

// ---- head: pooled/L -> Wh+bh -> BN(eval) -> gelu -> Wf+bf ----
__global__ __launch_bounds__(1024) void head_kernel(const float* __restrict__ pooled,
                                                    const float* __restrict__ Wh,
                                                    const float* __restrict__ bh,
                                                    const float* __restrict__ gam,
                                                    const float* __restrict__ bet,
                                                    const float* __restrict__ mean,
                                                    const float* __restrict__ var,
                                                    const float* __restrict__ Wf,
                                                    const float* __restrict__ bf,
                                                    float* __restrict__ out){
    __shared__ float y2[32][32];
    const int t = threadIdx.x;      // 0..1023
    const int b = t >> 5, c = t & 31;
    float a = bh[c];
    const float invL = 1.0f / (float)L_;
    #pragma unroll
    for (int d = 0; d < 32; d++) a += (pooled[b*32 + d] * invL) * Wh[d*32 + c];
    a = (a - mean[c]) * rsqrtf(var[c] + 1e-5f) * gam[c] + bet[c];
    y2[b][c] = gelu_f(a);
    __syncthreads();
    if (t < B_*DOUT_){
        const int b2 = t / DOUT_, j = t % DOUT_;
        float r = bf[j];
        #pragma unroll
        for (int c2 = 0; c2 < 32; c2++) r += y2[b2][c2] * Wf[c2*DOUT_ + j];
        out[t] = r;
    }
}

extern "C" void kernel_launch(void* const* d_in, const int* in_sizes, int n_in,
                              void* d_out, int out_size, void* d_ws, size_t ws_size,
                              hipStream_t stream){
    (void)in_sizes; (void)n_in; (void)out_size; (void)ws_size;
    const float* x    = (const float*)d_in[0];
    const float* fW1  = (const float*)d_in[1];
    const float* fb1  = (const float*)d_in[2];
    const float* fW2  = (const float*)d_in[3];
    const float* fb2  = (const float*)d_in[4];
    const float* Wh   = (const float*)d_in[5];
    const float* bh   = (const float*)d_in[6];
    const float* gam  = (const float*)d_in[7];
    const float* bet  = (const float*)d_in[8];
    const float* mean = (const float*)d_in[9];
    const float* var  = (const float*)d_in[10];
    const float* Wf   = (const float*)d_in[11];
    const float* bf   = (const float*)d_in[12];
    float* out = (float*)d_out;

    float* hbuf   = (float*)d_ws;                          // B*C*L floats (64 MB)
    float* part   = hbuf + (size_t)B_*C_*L_;               // B*H*S_*80 (~1.3 MB)
    float* kvn    = part + (size_t)B_*H_*S_*80;            // B*H*64
    float* pooled = kvn  + (size_t)B_*H_*64;               // B*C

    hipMemsetAsync(pooled, 0, B_*C_*sizeof(float), stream);

    dim3 sgrid(S_, H_, B_);
    dim3 bgrid(L_/TILE, B_);

    // block 0 (input = x, output -> hbuf)
    stats_kernel<<<sgrid, 256, 0, stream>>>(x, part);
    merge_kernel<<<B_*H_, 256, 0, stream>>>(part, kvn);
    block_kernel<false><<<bgrid, 256, 0, stream>>>(x, hbuf, kvn,
        fW1, fb1, fW2, fb2, nullptr);
    // block 1 (in-place on hbuf)
    stats_kernel<<<sgrid, 256, 0, stream>>>(hbuf, part);
    merge_kernel<<<B_*H_, 256, 0, stream>>>(part, kvn);
    block_kernel<false><<<bgrid, 256, 0, stream>>>(hbuf, hbuf, kvn,
        fW1 + C_*C_, fb1 + C_, fW2 + C_*C_, fb2 + C_, nullptr);
    // block 2 (no h write; reduce into pooled)
    stats_kernel<<<sgrid, 256, 0, stream>>>(hbuf, part);
    merge_kernel<<<B_*H_, 256, 0, stream>>>(part, kvn);
    block_kernel<true><<<bgrid, 256, 0, stream>>>(hbuf, nullptr, kvn,
        fW1 + 2*C_*C_, fb1 + 2*C_, fW2 + 2*C_*C_, fb2 + 2*C_, pooled);

    head_kernel<<<1, 1024, 0, stream>>>(pooled, Wh, bh, gam, bet, mean, var, Wf, bf, out);
}

// Round 8
// 276.449 us; speedup vs baseline: 2.5661x; 1.0787x over previous
//
#include <hip/hip_runtime.h>
#include <cstddef>

#define B_ 32
#define C_ 32
#define L_ 16384
#define H_ 4
#define DH_ 8
#define NB_ 3
#define DOUT_ 10
#define SEG_ 512
#define S_ (L_/SEG_)   // 32 segments per (b,head)

#define TILE 256
#define AST  40    // A_lds row stride (halfs): 80 B/row -> 16B-aligned b128 frag reads

typedef _Float16 f16_t;
typedef _Float16 f16x2 __attribute__((ext_vector_type(2)));
typedef _Float16 f16x4 __attribute__((ext_vector_type(4)));
typedef _Float16 f16x8 __attribute__((ext_vector_type(8)));
typedef float    f32x4 __attribute__((ext_vector_type(4)));

// Branch-free gelu via Abramowitz-Stegun 7.1.25 erf approximation (|eps|<=2.5e-5,
// far below the f16 rounding the activation path already carries).
__device__ __forceinline__ float gelu_f(float x){
    const float z  = fabsf(x) * 0.70710678118654752440f;
    const float t  = __builtin_amdgcn_rcpf(fmaf(0.47047f, z, 1.0f));
    const float e  = __expf(-z * z);
    float p = fmaf(t, 0.7478556f, -0.0958798f);
    p = fmaf(t, p, 0.3480242f);
    const float erfz = 1.0f - p * t * e;          // erf(|x|/sqrt(2))
    const float phi  = fmaf(copysignf(erfz, x), 0.5f, 0.5f);
    return x * phi;
}

#define RED_MAX32(v) do{ v = fmaxf(v, __shfl_xor(v,1));  v = fmaxf(v, __shfl_xor(v,2)); \
                         v = fmaxf(v, __shfl_xor(v,4));  v = fmaxf(v, __shfl_xor(v,8)); \
                         v = fmaxf(v, __shfl_xor(v,16)); }while(0)
#define RED_SUM32(v) do{ v += __shfl_xor(v,1);  v += __shfl_xor(v,2); \
                         v += __shfl_xor(v,4);  v += __shfl_xor(v,8); \
                         v += __shfl_xor(v,16); }while(0)

// ---- stats: per (b, head, seg) partial max / sumexp / kv over a 512-pos segment ----
// Templated on input element type: f32 for x (layer 0), f16 for hbuf (layers 1,2 --
// 32 MB, L3-resident right after the previous block wrote it).
// zpool: one WG zeroes pooled for the LAST layer (replaces the memset launch).
template<typename T>
__global__ __launch_bounds__(256) void stats_kernel(const T* __restrict__ h,
                                                    float* __restrict__ part,
                                                    float* __restrict__ zpool){
    const int seg = blockIdx.x;
    const int hd  = blockIdx.y;
    const int b   = blockIdx.z;
    const int t   = threadIdx.x;
    const int d   = t >> 5;   // 0..7  (feature within head); wave-half owns one d
    const int j   = t & 31;   // 0..31 (position lane)

    __shared__ float tile[8][SEG_];   // 16 KB
    __shared__ float sm[8];

    if (zpool != nullptr && blockIdx.x == 0 && blockIdx.y == 0 && blockIdx.z == 0)
        for (int i = t; i < B_*C_; i += 256) zpool[i] = 0.0f;

    const T* hb = h + (size_t)b * ((size_t)C_*L_) + (size_t)(hd*DH_)*L_ + (size_t)seg*SEG_;

    if constexpr (sizeof(T) == 4){
        for (int f = t; f < 8*SEG_/4; f += 256){
            const int row = f >> 7;
            const int c4  = (f & 127) << 2;
            *(f32x4*)&tile[row][c4] = *(const f32x4*)&hb[(size_t)row*L_ + c4];
        }
    } else {
        for (int f = t; f < 8*SEG_/8; f += 256){
            const int row = f >> 6;            // 64 f16x8 chunks per row
            const int c8  = (f & 63) << 3;
            const f16x8 v = *(const f16x8*)&hb[(size_t)row*L_ + c8];
            f32x4 lo = {(float)v[0], (float)v[1], (float)v[2], (float)v[3]};
            f32x4 hi = {(float)v[4], (float)v[5], (float)v[6], (float)v[7]};
            *(f32x4*)&tile[row][c8]     = lo;
            *(f32x4*)&tile[row][c8 + 4] = hi;
        }
    }
    __syncthreads();

    float m = -INFINITY;
    #pragma unroll
    for (int i = 0; i < SEG_/32; i++) m = fmaxf(m, tile[d][j + 32*i]);
    RED_MAX32(m);
    if (j == 0) sm[d] = m;
    const float m_d = m;

    float s = 0.0f;
    float kv[8];
    #pragma unroll
    for (int e = 0; e < 8; e++) kv[e] = 0.0f;
    #pragma unroll
    for (int i = 0; i < SEG_/32; i++){
        const int k = j + 32*i;
        const float ek = __expf(tile[d][k] - m_d);
        s += ek;
        #pragma unroll
        for (int e = 0; e < 8; e++) kv[e] = fmaf(ek, tile[e][k], kv[e]);
    }
    RED_SUM32(s);
    #pragma unroll
    for (int e = 0; e < 8; e++){ RED_SUM32(kv[e]); }
    __syncthreads();

    float* po = part + (size_t)((b*H_ + hd)*S_ + seg) * 80;
    if (j == 0){
        po[8 + d] = s;
        #pragma unroll
        for (int e = 0; e < 8; e++) po[16 + d*8 + e] = kv[e];
    }
    if (t < 8) po[t] = sm[t];
}

// ---- per-position attention (fp32) + FC1/FC2 via f16 MFMA ----
// Structure = R7 barrier-light body (ONE __syncthreads; Ash rows wave-private,
// R5-verified) + R4 merge-in-prologue (deletes 3 merge launches; the 32-segment
// reduction is L2-hot and overlaps the 32 in-flight h loads) + f16 hbuf I/O
// (halves inter-layer traffic; keeps stats1/2 L3-resident).
// waves_per_eu(3,4): only proven spill-free config (R1/R2: min>=5 crushes the
// live set to 40-48 VGPRs and spills 30-55 MB/dispatch).
// MFMA layouts (m89/m91-verified): A-frag lane holds A[m=lane&15][k=(lane>>4)*8+j];
// B-frag B[k][n=lane&15] (stored Bsh[n][k]); C/D col=lane&15, row=(lane>>4)*4+reg.
template<bool FIRST, bool LAST>
__global__ __launch_bounds__(256)
__attribute__((amdgpu_waves_per_eu(3, 4)))
void block_kernel(const void* hin,
                  f16_t* hout,
                  const float* __restrict__ part,
                  const float* __restrict__ W1,
                  const float* __restrict__ b1,
                  const float* __restrict__ W2,
                  const float* __restrict__ b2,
                  float* __restrict__ pooled){
    __shared__ __align__(16) f16_t Ash[TILE*AST];  // 20480 B
    __shared__ f16_t Bsh1[32*AST];                 // 2560 B: W1 as [n][k]
    __shared__ f16_t Bsh2[32*AST];                 // 2560 B
    __shared__ float sb1[32], sb2[32];
    __shared__ float kvsh[256];                    // merged kv/s: [head][d][e]
    __shared__ float pool[32];

    const int tid = threadIdx.x;
    const int b   = blockIdx.y;
    const int l0  = blockIdx.x * TILE;
    const int l   = l0 + tid;
    const size_t base = (size_t)b * ((size_t)C_*L_);

    // prologue: h loads issued first; weight staging + merge hide their latency
    float h[32];
    if constexpr (FIRST){
        const float* hf = (const float*)hin;
        #pragma unroll
        for (int c = 0; c < 32; c++) h[c] = hf[base + (size_t)c*L_ + l];
    } else {
        const f16_t* hh = (const f16_t*)hin;
        #pragma unroll
        for (int c = 0; c < 32; c++) h[c] = (float)hh[base + (size_t)c*L_ + l];
    }

    for (int i = tid; i < 1024; i += 256){
        const int k = i >> 5, n = i & 31;
        Bsh1[n*AST + k] = (f16_t)W1[i];
        Bsh2[n*AST + k] = (f16_t)W2[i];
    }
    if (tid < 32){ sb1[tid] = b1[tid]; sb2[tid] = b2[tid]; }
    if (LAST && tid < 32) pool[tid] = 0.0f;

    // merge segment partials -> kvsh (one (head,d,e) per thread; part is L2-hot)
    {
        const int hh_t = tid >> 6;      // head 0..3
        const int tt   = tid & 63;      // (d,e)
        const int dd   = tt >> 3;
        const float* pp = part + (size_t)(b*H_ + hh_t) * S_ * 80;
        float M = -INFINITY;
        for (int s2 = 0; s2 < S_; s2++) M = fmaxf(M, pp[s2*80 + dd]);
        float ssum = 0.0f, kvs = 0.0f;
        for (int s2 = 0; s2 < S_; s2++){
            const float sc = __expf(pp[s2*80 + dd] - M);
            ssum = fmaf(pp[s2*80 + 8  + dd], sc, ssum);
            kvs  = fmaf(pp[s2*80 + 16 + tt], sc, kvs);
        }
        kvsh[tid] = kvs / ssum;
    }
    __syncthreads();   // the ONLY barrier: kvsh + weights (+ LAST pool) visible

    // ---- phase 1: per-thread fp32 attention (kvsh reads are same-address -> broadcast)
    float attn[32];
    #pragma unroll
    for (int hh = 0; hh < 4; hh++){
        float mq = h[hh*8];
        #pragma unroll
        for (int d2 = 1; d2 < 8; d2++) mq = fmaxf(mq, h[hh*8 + d2]);
        float es[8]; float qs = 0.f;
        #pragma unroll
        for (int d2 = 0; d2 < 8; d2++){ es[d2] = __expf(h[hh*8 + d2] - mq); qs += es[d2]; }
        const float inv = __builtin_amdgcn_rcpf(qs);
        #pragma unroll
        for (int e = 0; e < 8; e++){
            float a = 0.f;
            #pragma unroll
            for (int d2 = 0; d2 < 8; d2++) a += es[d2] * kvsh[hh*64 + d2*8 + e];
            attn[hh*8 + e] = a * inv;
        }
    }

    // attn -> f16 A matrix in LDS (wave-private rows; no barrier needed below)
    #pragma unroll
    for (int k2 = 0; k2 < 32; k2 += 2){
        f16x2 pr = { (f16_t)attn[k2], (f16_t)attn[k2+1] };
        *(f16x2*)&Ash[tid*AST + k2] = pr;
    }

    // ---- phase 2: MFMA FCs (all Ash traffic wave-private -> zero barriers)
    const int wv   = tid >> 6;
    const int lane = tid & 63;
    const int lr   = lane & 15;
    const int lk   = lane >> 4;
    const f32x4 zero = {0.f, 0.f, 0.f, 0.f};

    f16x8 a[4], bw[2];
    f32x4 d[8];

    // FC1
    #pragma unroll
    for (int mt = 0; mt < 4; mt++)
        a[mt] = *(const f16x8*)&Ash[(wv*64 + mt*16 + lr)*AST + lk*8];
    #pragma unroll
    for (int nt = 0; nt < 2; nt++)
        bw[nt] = *(const f16x8*)&Bsh1[(nt*16 + lr)*AST + lk*8];
    #pragma unroll
    for (int nt = 0; nt < 2; nt++)
        #pragma unroll
        for (int mt = 0; mt < 4; mt++)
            d[nt*4+mt] = __builtin_amdgcn_mfma_f32_16x16x32_f16(a[mt], bw[nt], zero, 0, 0, 0);

    // bias + gelu + writeback as A2 (wave-private rows; no barrier)
    #pragma unroll
    for (int nt = 0; nt < 2; nt++){
        const float bias = sb1[nt*16 + lr];
        #pragma unroll
        for (int mt = 0; mt < 4; mt++)
            #pragma unroll
            for (int r = 0; r < 4; r++){
                const float v = gelu_f(d[nt*4+mt][r] + bias);
                Ash[(wv*64 + mt*16 + lk*4 + r)*AST + (nt*16 + lr)] = (f16_t)v;
            }
    }

    // FC2
    #pragma unroll
    for (int mt = 0; mt < 4; mt++)
        a[mt] = *(const f16x8*)&Ash[(wv*64 + mt*16 + lr)*AST + lk*8];
    #pragma unroll
    for (int nt = 0; nt < 2; nt++)
        bw[nt] = *(const f16x8*)&Bsh2[(nt*16 + lr)*AST + lk*8];
    #pragma unroll
    for (int nt = 0; nt < 2; nt++)
        #pragma unroll
        for (int mt = 0; mt < 4; mt++)
            d[nt*4+mt] = __builtin_amdgcn_mfma_f32_16x16x32_f16(a[mt], bw[nt], zero, 0, 0, 0);

    // bias + gelu on D (fp32)
    #pragma unroll
    for (int nt = 0; nt < 2; nt++){
        const float bias = sb2[nt*16 + lr];
        #pragma unroll
        for (int mt = 0; mt < 4; mt++)
            #pragma unroll
            for (int r = 0; r < 4; r++)
                d[nt*4+mt][r] = gelu_f(d[nt*4+mt][r] + bias);
    }

    if (!LAST){
        // direct f16x4 store: lane owns 4 consecutive positions of channel nt*16+lr;
        // 4 lanes (lk=0..3) cover 16 contiguous positions -> 32 B contiguous chunks
        #pragma unroll
        for (int nt = 0; nt < 2; nt++)
            #pragma unroll
            for (int mt = 0; mt < 4; mt++){
                const f32x4 dv = d[nt*4+mt];
                f16x4 hv = { (f16_t)dv[0], (f16_t)dv[1], (f16_t)dv[2], (f16_t)dv[3] };
                *(f16x4*)&hout[base + (size_t)(nt*16 + lr)*L_
                               + l0 + wv*64 + mt*16 + lk*4] = hv;
            }
    } else {
        #pragma unroll
        for (int nt = 0; nt < 2; nt++){
            float ps = 0.f;
            #pragma unroll
            for (int mt = 0; mt < 4; mt++)
                ps += d[nt*4+mt][0] + d[nt*4+mt][1] + d[nt*4+mt][2] + d[nt*4+mt][3];
            atomicAdd(&pool[nt*16 + lr], ps);
        }
        __syncthreads();
        if (tid < 32) atomicAdd(&pooled[b*32 + tid], pool[tid]);
    }
}

// ---- head: pooled/L -> Wh+bh -> BN(eval) -> gelu -> Wf+bf ----
__global__ __launch_bounds__(1024) void head_kernel(const float* __restrict__ pooled,
                                                    const float* __restrict__ Wh,
                                                    const float* __restrict__ bh,
                                                    const float* __restrict__ gam,
                                                    const float* __restrict__ bet,
                                                    const float* __restrict__ mean,
                                                    const float* __restrict__ var,
                                                    const float* __restrict__ Wf,
                                                    const float* __restrict__ bf,
                                                    float* __restrict__ out){
    __shared__ float y2[32][32];
    const int t = threadIdx.x;      // 0..1023
    const int b = t >> 5, c = t & 31;
    float a = bh[c];
    const float invL = 1.0f / (float)L_;
    #pragma unroll
    for (int d = 0; d < 32; d++) a += (pooled[b*32 + d] * invL) * Wh[d*32 + c];
    a = (a - mean[c]) * rsqrtf(var[c] + 1e-5f) * gam[c] + bet[c];
    y2[b][c] = gelu_f(a);
    __syncthreads();
    if (t < B_*DOUT_){
        const int b2 = t / DOUT_, j = t % DOUT_;
        float r = bf[j];
        #pragma unroll
        for (int c2 = 0; c2 < 32; c2++) r += y2[b2][c2] * Wf[c2*DOUT_ + j];
        out[t] = r;
    }
}

extern "C" void kernel_launch(void* const* d_in, const int* in_sizes, int n_in,
                              void* d_out, int out_size, void* d_ws, size_t ws_size,
                              hipStream_t stream){
    (void)in_sizes; (void)n_in; (void)out_size; (void)ws_size;
    const float* x    = (const float*)d_in[0];
    const float* fW1  = (const float*)d_in[1];
    const float* fb1  = (const float*)d_in[2];
    const float* fW2  = (const float*)d_in[3];
    const float* fb2  = (const float*)d_in[4];
    const float* Wh   = (const float*)d_in[5];
    const float* bh   = (const float*)d_in[6];
    const float* gam  = (const float*)d_in[7];
    const float* bet  = (const float*)d_in[8];
    const float* mean = (const float*)d_in[9];
    const float* var  = (const float*)d_in[10];
    const float* Wf   = (const float*)d_in[11];
    const float* bf   = (const float*)d_in[12];
    float* out = (float*)d_out;

    f16_t* hbuf   = (f16_t*)d_ws;                                  // B*C*L f16 (32 MB)
    float* part   = (float*)((char*)d_ws + (size_t)B_*C_*L_*2);    // B*H*S_*80 (~1.3 MB)
    float* pooled = part + (size_t)B_*H_*S_*80;                    // B*C

    dim3 sgrid(S_, H_, B_);
    dim3 bgrid(L_/TILE, B_);

    // 7 dispatches total (R7 had 11; ~4-5 us gap per launch boundary).
    // block 0 (input = x f32, output -> hbuf f16)
    stats_kernel<float><<<sgrid, 256, 0, stream>>>(x, part, nullptr);
    block_kernel<true, false><<<bgrid, 256, 0, stream>>>(x, hbuf, part,
        fW1, fb1, fW2, fb2, nullptr);
    // block 1 (in-place on hbuf f16)
    stats_kernel<f16_t><<<sgrid, 256, 0, stream>>>(hbuf, part, nullptr);
    block_kernel<false, false><<<bgrid, 256, 0, stream>>>(hbuf, hbuf, part,
        fW1 + C_*C_, fb1 + C_, fW2 + C_*C_, fb2 + C_, nullptr);
    // block 2 (no h write; reduce into pooled; stats2 zeroes pooled)
    stats_kernel<f16_t><<<sgrid, 256, 0, stream>>>(hbuf, part, pooled);
    block_kernel<false, true><<<bgrid, 256, 0, stream>>>(hbuf, nullptr, part,
        fW1 + 2*C_*C_, fb1 + 2*C_, fW2 + 2*C_*C_, fb2 + 2*C_, pooled);

    head_kernel<<<1, 1024, 0, stream>>>(pooled, Wh, bh, gam, bet, mean, var, Wf, bf, out);
}

// Round 9
// 274.913 us; speedup vs baseline: 2.5804x; 1.0056x over previous
//
#include <hip/hip_runtime.h>
#include <cstddef>

#define B_ 32
#define C_ 32
#define L_ 16384
#define H_ 4
#define DH_ 8
#define NB_ 3
#define DOUT_ 10
#define SEG_ 512
#define S_ (L_/SEG_)   // 32 segments per (b,head)

#define TILE 256
#define AST  40    // A_lds row stride (halfs): 80 B/row -> 16B-aligned b128 frag reads

typedef _Float16 f16_t;
typedef _Float16 f16x2 __attribute__((ext_vector_type(2)));
typedef _Float16 f16x4 __attribute__((ext_vector_type(4)));
typedef _Float16 f16x8 __attribute__((ext_vector_type(8)));
typedef float    f32x4 __attribute__((ext_vector_type(4)));

// Branch-free gelu via Abramowitz-Stegun 7.1.25 erf approximation (|eps|<=2.5e-5,
// far below the f16 rounding the activation path already carries).
__device__ __forceinline__ float gelu_f(float x){
    const float z  = fabsf(x) * 0.70710678118654752440f;
    const float t  = __builtin_amdgcn_rcpf(fmaf(0.47047f, z, 1.0f));
    const float e  = __expf(-z * z);
    float p = fmaf(t, 0.7478556f, -0.0958798f);
    p = fmaf(t, p, 0.3480242f);
    const float erfz = 1.0f - p * t * e;          // erf(|x|/sqrt(2))
    const float phi  = fmaf(copysignf(erfz, x), 0.5f, 0.5f);
    return x * phi;
}

#define RED_MAX32(v) do{ v = fmaxf(v, __shfl_xor(v,1));  v = fmaxf(v, __shfl_xor(v,2)); \
                         v = fmaxf(v, __shfl_xor(v,4));  v = fmaxf(v, __shfl_xor(v,8)); \
                         v = fmaxf(v, __shfl_xor(v,16)); }while(0)
#define RED_SUM32(v) do{ v += __shfl_xor(v,1);  v += __shfl_xor(v,2); \
                         v += __shfl_xor(v,4);  v += __shfl_xor(v,8); \
                         v += __shfl_xor(v,16); }while(0)

// ---- stats: per (b, head, seg) partial max / sumexp / kv over a 512-pos segment ----
// f32 for x (layer 0), f16 for hbuf (layers 1,2 -- 32 MB, L3-resident).
// zpool: one WG zeroes pooled for the LAST layer (replaces the memset launch).
template<typename T>
__global__ __launch_bounds__(256) void stats_kernel(const T* __restrict__ h,
                                                    float* __restrict__ part,
                                                    float* __restrict__ zpool){
    const int seg = blockIdx.x;
    const int hd  = blockIdx.y;
    const int b   = blockIdx.z;
    const int t   = threadIdx.x;
    const int d   = t >> 5;   // 0..7  (feature within head); wave-half owns one d
    const int j   = t & 31;   // 0..31 (position lane)

    __shared__ float tile[8][SEG_];   // 16 KB
    __shared__ float sm[8];

    if (zpool != nullptr && blockIdx.x == 0 && blockIdx.y == 0 && blockIdx.z == 0)
        for (int i = t; i < B_*C_; i += 256) zpool[i] = 0.0f;

    const T* hb = h + (size_t)b * ((size_t)C_*L_) + (size_t)(hd*DH_)*L_ + (size_t)seg*SEG_;

    if constexpr (sizeof(T) == 4){
        for (int f = t; f < 8*SEG_/4; f += 256){
            const int row = f >> 7;
            const int c4  = (f & 127) << 2;
            *(f32x4*)&tile[row][c4] = *(const f32x4*)&hb[(size_t)row*L_ + c4];
        }
    } else {
        for (int f = t; f < 8*SEG_/8; f += 256){
            const int row = f >> 6;            // 64 f16x8 chunks per row
            const int c8  = (f & 63) << 3;
            const f16x8 v = *(const f16x8*)&hb[(size_t)row*L_ + c8];
            f32x4 lo = {(float)v[0], (float)v[1], (float)v[2], (float)v[3]};
            f32x4 hi = {(float)v[4], (float)v[5], (float)v[6], (float)v[7]};
            *(f32x4*)&tile[row][c8]     = lo;
            *(f32x4*)&tile[row][c8 + 4] = hi;
        }
    }
    __syncthreads();

    float m = -INFINITY;
    #pragma unroll
    for (int i = 0; i < SEG_/32; i++) m = fmaxf(m, tile[d][j + 32*i]);
    RED_MAX32(m);
    if (j == 0) sm[d] = m;
    const float m_d = m;

    float s = 0.0f;
    float kv[8];
    #pragma unroll
    for (int e = 0; e < 8; e++) kv[e] = 0.0f;
    #pragma unroll
    for (int i = 0; i < SEG_/32; i++){
        const int k = j + 32*i;
        const float ek = __expf(tile[d][k] - m_d);
        s += ek;
        #pragma unroll
        for (int e = 0; e < 8; e++) kv[e] = fmaf(ek, tile[e][k], kv[e]);
    }
    RED_SUM32(s);
    #pragma unroll
    for (int e = 0; e < 8; e++){ RED_SUM32(kv[e]); }
    __syncthreads();

    float* po = part + (size_t)((b*H_ + hd)*S_ + seg) * 80;
    if (j == 0){
        po[8 + d] = s;
        #pragma unroll
        for (int e = 0; e < 8; e++) po[16 + d*8 + e] = kv[e];
    }
    if (t < 8) po[t] = sm[t];
}

// ---- per-position softmax P + FC1/FC2 via f16 MFMA, with kv FOLDED INTO W1 ----
// Algebra: attn = P @ blockdiag(kv) (P = per-head feature softmax, kv per batch)
// => attn @ W1 = P @ W1eff,  W1eff = blockdiag(kv) @ W1  (computed once per WG,
// 32 fma/thread, after the in-prologue merge produces kvsh). This deletes the
// per-position 256-fma es*kv matmul and its 256 LDS broadcast reads -- the
// largest VALU/LDS term in the per-position path (R3/R4 PMC: VALUBusy 53%).
// Barriers: TWO (kvsh, then W1eff/Bsh). Ash rows remain wave-private
// (R5-verified: no barrier for attn-write->FC1-read or FC1-writeback->FC2-read).
// waves_per_eu(3,4): only proven spill-free config (R1/R2: min>=5 -> 30-55 MB
// of scratch spill traffic per dispatch).
// MFMA layouts (m89/m91-verified): A-frag lane holds A[m=lane&15][k=(lane>>4)*8+j];
// B-frag B[k][n=lane&15] (stored Bsh[n][k]); C/D col=lane&15, row=(lane>>4)*4+reg.
template<bool FIRST, bool LAST>
__global__ __launch_bounds__(256)
__attribute__((amdgpu_waves_per_eu(3, 4)))
void block_kernel(const void* hin,
                  f16_t* hout,
                  const float* __restrict__ part,
                  const float* __restrict__ W1,
                  const float* __restrict__ b1,
                  const float* __restrict__ W2,
                  const float* __restrict__ b2,
                  float* __restrict__ pooled){
    __shared__ __align__(16) f16_t Ash[TILE*AST];  // 20480 B: P matrix [pos][k]
    __shared__ f16_t Bsh1[32*AST];                 // 2560 B: W1eff as [n][k]
    __shared__ f16_t Bsh2[32*AST];                 // 2560 B: W2 as [n][k]
    __shared__ float sb1[32], sb2[32];
    __shared__ float kvsh[256];                    // merged kv/s: [head][d][e]
    __shared__ float pool[32];

    const int tid = threadIdx.x;
    const int b   = blockIdx.y;
    const int l0  = blockIdx.x * TILE;
    const int l   = l0 + tid;
    const size_t base = (size_t)b * ((size_t)C_*L_);

    // prologue: h loads issued first; W2 staging + merge hide their latency
    float h[32];
    if constexpr (FIRST){
        const float* hf = (const float*)hin;
        #pragma unroll
        for (int c = 0; c < 32; c++) h[c] = hf[base + (size_t)c*L_ + l];
    } else {
        const f16_t* hh = (const f16_t*)hin;
        #pragma unroll
        for (int c = 0; c < 32; c++) h[c] = (float)hh[base + (size_t)c*L_ + l];
    }

    for (int i = tid; i < 1024; i += 256){
        const int k = i >> 5, n = i & 31;
        Bsh2[n*AST + k] = (f16_t)W2[i];
    }
    if (tid < 32){ sb1[tid] = b1[tid]; sb2[tid] = b2[tid]; }
    if (LAST && tid < 32) pool[tid] = 0.0f;

    // merge segment partials -> kvsh (one (head,d,e) per thread; part is L2-hot)
    {
        const int hh_t = tid >> 6;      // head 0..3
        const int tt   = tid & 63;      // (d,e)
        const int dd   = tt >> 3;
        const float* pp = part + (size_t)(b*H_ + hh_t) * S_ * 80;
        float M = -INFINITY;
        for (int s2 = 0; s2 < S_; s2++) M = fmaxf(M, pp[s2*80 + dd]);
        float ssum = 0.0f, kvs = 0.0f;
        for (int s2 = 0; s2 < S_; s2++){
            const float sc = __expf(pp[s2*80 + dd] - M);
            ssum = fmaf(pp[s2*80 + 8  + dd], sc, ssum);
            kvs  = fmaf(pp[s2*80 + 16 + tt], sc, kvs);
        }
        kvsh[tid] = kvs / ssum;
    }

    // per-position softmax P -> Ash (one ds_write_b128 per head; wave-private rows)
    #pragma unroll
    for (int hh = 0; hh < 4; hh++){
        float mq = h[hh*8];
        #pragma unroll
        for (int d2 = 1; d2 < 8; d2++) mq = fmaxf(mq, h[hh*8 + d2]);
        float es[8]; float qs = 0.f;
        #pragma unroll
        for (int d2 = 0; d2 < 8; d2++){ es[d2] = __expf(h[hh*8 + d2] - mq); qs += es[d2]; }
        const float inv = __builtin_amdgcn_rcpf(qs);
        f16x8 pv;
        #pragma unroll
        for (int d2 = 0; d2 < 8; d2++) pv[d2] = (f16_t)(es[d2] * inv);
        *(f16x8*)&Ash[tid*AST + hh*8] = pv;
    }
    __syncthreads();   // barrier 1: kvsh visible

    // W1eff = blockdiag(kv) @ W1 -> Bsh1.  thread -> (row = c_in, 4 cols)
    {
        const int row = tid >> 3;            // c_in 0..31
        const int hh2 = row >> 3;            // head of this input channel
        const int q   = tid & 7;             // col group: n = q*4 + j
        float kvr[8];
        #pragma unroll
        for (int e = 0; e < 8; e++) kvr[e] = kvsh[row*8 + e];
        f32x4 acc = {0.f, 0.f, 0.f, 0.f};
        #pragma unroll
        for (int e = 0; e < 8; e++){
            const f32x4 w = *(const f32x4*)&W1[(hh2*8 + e)*32 + q*4];
            acc += kvr[e] * w;
        }
        #pragma unroll
        for (int j2 = 0; j2 < 4; j2++)
            Bsh1[(q*4 + j2)*AST + row] = (f16_t)acc[j2];
    }
    __syncthreads();   // barrier 2: Bsh1 (+Bsh2, sb) visible

    // ---- MFMA FCs (all Ash traffic wave-private -> zero further barriers)
    const int wv   = tid >> 6;
    const int lane = tid & 63;
    const int lr   = lane & 15;
    const int lk   = lane >> 4;
    const f32x4 zero = {0.f, 0.f, 0.f, 0.f};

    f16x8 a[4], bw[2];
    f32x4 d[8];

    // FC1 (A = P, B = W1eff)
    #pragma unroll
    for (int mt = 0; mt < 4; mt++)
        a[mt] = *(const f16x8*)&Ash[(wv*64 + mt*16 + lr)*AST + lk*8];
    #pragma unroll
    for (int nt = 0; nt < 2; nt++)
        bw[nt] = *(const f16x8*)&Bsh1[(nt*16 + lr)*AST + lk*8];
    #pragma unroll
    for (int nt = 0; nt < 2; nt++)
        #pragma unroll
        for (int mt = 0; mt < 4; mt++)
            d[nt*4+mt] = __builtin_amdgcn_mfma_f32_16x16x32_f16(a[mt], bw[nt], zero, 0, 0, 0);

    // bias + gelu + writeback as A2 (wave-private rows; no barrier)
    #pragma unroll
    for (int nt = 0; nt < 2; nt++){
        const float bias = sb1[nt*16 + lr];
        #pragma unroll
        for (int mt = 0; mt < 4; mt++)
            #pragma unroll
            for (int r = 0; r < 4; r++){
                const float v = gelu_f(d[nt*4+mt][r] + bias);
                Ash[(wv*64 + mt*16 + lk*4 + r)*AST + (nt*16 + lr)] = (f16_t)v;
            }
    }

    // FC2
    #pragma unroll
    for (int mt = 0; mt < 4; mt++)
        a[mt] = *(const f16x8*)&Ash[(wv*64 + mt*16 + lr)*AST + lk*8];
    #pragma unroll
    for (int nt = 0; nt < 2; nt++)
        bw[nt] = *(const f16x8*)&Bsh2[(nt*16 + lr)*AST + lk*8];
    #pragma unroll
    for (int nt = 0; nt < 2; nt++)
        #pragma unroll
        for (int mt = 0; mt < 4; mt++)
            d[nt*4+mt] = __builtin_amdgcn_mfma_f32_16x16x32_f16(a[mt], bw[nt], zero, 0, 0, 0);

    // bias + gelu on D (fp32)
    #pragma unroll
    for (int nt = 0; nt < 2; nt++){
        const float bias = sb2[nt*16 + lr];
        #pragma unroll
        for (int mt = 0; mt < 4; mt++)
            #pragma unroll
            for (int r = 0; r < 4; r++)
                d[nt*4+mt][r] = gelu_f(d[nt*4+mt][r] + bias);
    }

    if (!LAST){
        // direct f16x4 store: lane owns 4 consecutive positions of channel nt*16+lr
        #pragma unroll
        for (int nt = 0; nt < 2; nt++)
            #pragma unroll
            for (int mt = 0; mt < 4; mt++){
                const f32x4 dv = d[nt*4+mt];
                f16x4 hv = { (f16_t)dv[0], (f16_t)dv[1], (f16_t)dv[2], (f16_t)dv[3] };
                *(f16x4*)&hout[base + (size_t)(nt*16 + lr)*L_
                               + l0 + wv*64 + mt*16 + lk*4] = hv;
            }
    } else {
        #pragma unroll
        for (int nt = 0; nt < 2; nt++){
            float ps = 0.f;
            #pragma unroll
            for (int mt = 0; mt < 4; mt++)
                ps += d[nt*4+mt][0] + d[nt*4+mt][1] + d[nt*4+mt][2] + d[nt*4+mt][3];
            atomicAdd(&pool[nt*16 + lr], ps);
        }
        __syncthreads();
        if (tid < 32) atomicAdd(&pooled[b*32 + tid], pool[tid]);
    }
}

// ---- head: pooled/L -> Wh+bh -> BN(eval) -> gelu -> Wf+bf ----
__global__ __launch_bounds__(1024) void head_kernel(const float* __restrict__ pooled,
                                                    const float* __restrict__ Wh,
                                                    const float* __restrict__ bh,
                                                    const float* __restrict__ gam,
                                                    const float* __restrict__ bet,
                                                    const float* __restrict__ mean,
                                                    const float* __restrict__ var,
                                                    const float* __restrict__ Wf,
                                                    const float* __restrict__ bf,
                                                    float* __restrict__ out){
    __shared__ float y2[32][32];
    const int t = threadIdx.x;      // 0..1023
    const int b = t >> 5, c = t & 31;
    float a = bh[c];
    const float invL = 1.0f / (float)L_;
    #pragma unroll
    for (int d = 0; d < 32; d++) a += (pooled[b*32 + d] * invL) * Wh[d*32 + c];
    a = (a - mean[c]) * rsqrtf(var[c] + 1e-5f) * gam[c] + bet[c];
    y2[b][c] = gelu_f(a);
    __syncthreads();
    if (t < B_*DOUT_){
        const int b2 = t / DOUT_, j = t % DOUT_;
        float r = bf[j];
        #pragma unroll
        for (int c2 = 0; c2 < 32; c2++) r += y2[b2][c2] * Wf[c2*DOUT_ + j];
        out[t] = r;
    }
}

extern "C" void kernel_launch(void* const* d_in, const int* in_sizes, int n_in,
                              void* d_out, int out_size, void* d_ws, size_t ws_size,
                              hipStream_t stream){
    (void)in_sizes; (void)n_in; (void)out_size; (void)ws_size;
    const float* x    = (const float*)d_in[0];
    const float* fW1  = (const float*)d_in[1];
    const float* fb1  = (const float*)d_in[2];
    const float* fW2  = (const float*)d_in[3];
    const float* fb2  = (const float*)d_in[4];
    const float* Wh   = (const float*)d_in[5];
    const float* bh   = (const float*)d_in[6];
    const float* gam  = (const float*)d_in[7];
    const float* bet  = (const float*)d_in[8];
    const float* mean = (const float*)d_in[9];
    const float* var  = (const float*)d_in[10];
    const float* Wf   = (const float*)d_in[11];
    const float* bf   = (const float*)d_in[12];
    float* out = (float*)d_out;

    f16_t* hbuf   = (f16_t*)d_ws;                                  // B*C*L f16 (32 MB)
    float* part   = (float*)((char*)d_ws + (size_t)B_*C_*L_*2);    // B*H*S_*80 (~1.3 MB)
    float* pooled = part + (size_t)B_*H_*S_*80;                    // B*C

    dim3 sgrid(S_, H_, B_);
    dim3 bgrid(L_/TILE, B_);

    // 7 dispatches total.
    // block 0 (input = x f32, output -> hbuf f16)
    stats_kernel<float><<<sgrid, 256, 0, stream>>>(x, part, nullptr);
    block_kernel<true, false><<<bgrid, 256, 0, stream>>>(x, hbuf, part,
        fW1, fb1, fW2, fb2, nullptr);
    // block 1 (in-place on hbuf f16)
    stats_kernel<f16_t><<<sgrid, 256, 0, stream>>>(hbuf, part, nullptr);
    block_kernel<false, false><<<bgrid, 256, 0, stream>>>(hbuf, hbuf, part,
        fW1 + C_*C_, fb1 + C_, fW2 + C_*C_, fb2 + C_, nullptr);
    // block 2 (no h write; reduce into pooled; stats2 zeroes pooled)
    stats_kernel<f16_t><<<sgrid, 256, 0, stream>>>(hbuf, part, pooled);
    block_kernel<false, true><<<bgrid, 256, 0, stream>>>(hbuf, nullptr, part,
        fW1 + 2*C_*C_, fb1 + 2*C_, fW2 + 2*C_*C_, fb2 + 2*C_, pooled);

    head_kernel<<<1, 1024, 0, stream>>>(pooled, Wh, bh, gam, bet, mean, var, Wf, bf, out);
}

// Round 10
// 270.107 us; speedup vs baseline: 2.6263x; 1.0178x over previous
//
#include <hip/hip_runtime.h>
#include <cstddef>

#define B_ 32
#define C_ 32
#define L_ 16384
#define H_ 4
#define DH_ 8
#define NB_ 3
#define DOUT_ 10
#define SEG_ 512
#define S_ (L_/SEG_)   // 32 segments per (b,head)

#define TILE 256
#define AST  40    // A_lds row stride (halfs): 80 B/row; cols 32..39 = "holes" hold W1eff/W2

typedef _Float16 f16_t;
typedef _Float16 f16x2 __attribute__((ext_vector_type(2)));
typedef _Float16 f16x4 __attribute__((ext_vector_type(4)));
typedef _Float16 f16x8 __attribute__((ext_vector_type(8)));
typedef float    f32x4 __attribute__((ext_vector_type(4)));

// Branch-free gelu via Abramowitz-Stegun 7.1.25 erf approximation (|eps|<=2.5e-5,
// far below the f16 rounding the activation path already carries).
__device__ __forceinline__ float gelu_f(float x){
    const float z  = fabsf(x) * 0.70710678118654752440f;
    const float t  = __builtin_amdgcn_rcpf(fmaf(0.47047f, z, 1.0f));
    const float e  = __expf(-z * z);
    float p = fmaf(t, 0.7478556f, -0.0958798f);
    p = fmaf(t, p, 0.3480242f);
    const float erfz = 1.0f - p * t * e;          // erf(|x|/sqrt(2))
    const float phi  = fmaf(copysignf(erfz, x), 0.5f, 0.5f);
    return x * phi;
}

#define RED_MAX32(v) do{ v = fmaxf(v, __shfl_xor(v,1));  v = fmaxf(v, __shfl_xor(v,2)); \
                         v = fmaxf(v, __shfl_xor(v,4));  v = fmaxf(v, __shfl_xor(v,8)); \
                         v = fmaxf(v, __shfl_xor(v,16)); }while(0)
#define RED_SUM32(v) do{ v += __shfl_xor(v,1);  v += __shfl_xor(v,2); \
                         v += __shfl_xor(v,4);  v += __shfl_xor(v,8); \
                         v += __shfl_xor(v,16); }while(0)

// ---- stats: per (b, head, seg) partial max / sumexp / kv over a 512-pos segment ----
// f32 for x (layer 0), f16 for hbuf (layers 1,2 -- 32 MB, L3-resident).
// zpool: one WG zeroes pooled for the LAST layer (replaces the memset launch).
template<typename T>
__global__ __launch_bounds__(256) void stats_kernel(const T* __restrict__ h,
                                                    float* __restrict__ part,
                                                    float* __restrict__ zpool){
    const int seg = blockIdx.x;
    const int hd  = blockIdx.y;
    const int b   = blockIdx.z;
    const int t   = threadIdx.x;
    const int d   = t >> 5;   // 0..7  (feature within head); wave-half owns one d
    const int j   = t & 31;   // 0..31 (position lane)

    __shared__ float tile[8][SEG_];   // 16 KB
    __shared__ float sm[8];

    if (zpool != nullptr && blockIdx.x == 0 && blockIdx.y == 0 && blockIdx.z == 0)
        for (int i = t; i < B_*C_; i += 256) zpool[i] = 0.0f;

    const T* hb = h + (size_t)b * ((size_t)C_*L_) + (size_t)(hd*DH_)*L_ + (size_t)seg*SEG_;

    if constexpr (sizeof(T) == 4){
        for (int f = t; f < 8*SEG_/4; f += 256){
            const int row = f >> 7;
            const int c4  = (f & 127) << 2;
            *(f32x4*)&tile[row][c4] = *(const f32x4*)&hb[(size_t)row*L_ + c4];
        }
    } else {
        for (int f = t; f < 8*SEG_/8; f += 256){
            const int row = f >> 6;            // 64 f16x8 chunks per row
            const int c8  = (f & 63) << 3;
            const f16x8 v = *(const f16x8*)&hb[(size_t)row*L_ + c8];
            f32x4 lo = {(float)v[0], (float)v[1], (float)v[2], (float)v[3]};
            f32x4 hi = {(float)v[4], (float)v[5], (float)v[6], (float)v[7]};
            *(f32x4*)&tile[row][c8]     = lo;
            *(f32x4*)&tile[row][c8 + 4] = hi;
        }
    }
    __syncthreads();

    float m = -INFINITY;
    #pragma unroll
    for (int i = 0; i < SEG_/32; i++) m = fmaxf(m, tile[d][j + 32*i]);
    RED_MAX32(m);
    if (j == 0) sm[d] = m;
    const float m_d = m;

    float s = 0.0f;
    float kv[8];
    #pragma unroll
    for (int e = 0; e < 8; e++) kv[e] = 0.0f;
    #pragma unroll
    for (int i = 0; i < SEG_/32; i++){
        const int k = j + 32*i;
        const float ek = __expf(tile[d][k] - m_d);
        s += ek;
        #pragma unroll
        for (int e = 0; e < 8; e++) kv[e] = fmaf(ek, tile[e][k], kv[e]);
    }
    RED_SUM32(s);
    #pragma unroll
    for (int e = 0; e < 8; e++){ RED_SUM32(kv[e]); }
    __syncthreads();

    float* po = part + (size_t)((b*H_ + hd)*S_ + seg) * 80;
    if (j == 0){
        po[8 + d] = s;
        #pragma unroll
        for (int e = 0; e < 8; e++) po[16 + d*8 + e] = kv[e];
    }
    if (t < 8) po[t] = sm[t];
}

// ---- per-position softmax P + FC1/FC2 via f16 MFMA ----
// R10 structure (R9 post-mortem: latency/residency-bound, NOT VALU-bound):
//  * REGISTER-DIRECT A-FRAGS: lane (lk,lr) of wave wv loads channels lk*8..+7
//    (= head lk) for the 4 positions wv*64+mt*16+lr. Per-head softmax is fully
//    lane-local, and the normalized P IS the MFMA A-fragment -- no LDS for A.
//  * WEIGHTS IN Ash HOLES: AST=40 leaves 8 halfs/row unused; W1eff occupies
//    hole-rows 0..127, W2 hole-rows 128..255 (16B-aligned f16x8 frag reads).
//    LDS = 20480 B exactly -> 8 WG/CU (grid = 2048 = 8/CU: single round).
//  * SHUFFLE-COMBINE MERGE: lane reduces 4 segments (vec4 kv loads) then a
//    3-step shfl_xor logsumexp combine over the 8 q-lanes -> full kvn row in
//    registers; W1eff build self-contained -> ONE __syncthreads total.
//  * biases via 2 scalar global loads/lane; LAST pooling via shfl+global atomics.
// waves_per_eu(3,4): only proven spill-free config (R1/R2).
// MFMA layouts (m89/m91-verified): A-frag lane holds A[m=lane&15][k=(lane>>4)*8+j];
// B-frag B[k][n=lane&15]; C/D col=lane&15, row=(lane>>4)*4+reg.
template<bool FIRST, bool LAST>
__global__ __launch_bounds__(256)
__attribute__((amdgpu_waves_per_eu(3, 4)))
void block_kernel(const void* hin,
                  f16_t* hout,
                  const float* __restrict__ part,
                  const float* __restrict__ W1,
                  const float* __restrict__ b1,
                  const float* __restrict__ W2,
                  const float* __restrict__ b2,
                  float* __restrict__ pooled){
    __shared__ __align__(16) f16_t AO[TILE*AST];   // 20480 B total LDS

    const int tid  = threadIdx.x;
    const int b    = blockIdx.y;
    const int l0   = blockIdx.x * TILE;
    const size_t base = (size_t)b * ((size_t)C_*L_);

    const int wv   = tid >> 6;
    const int lane = tid & 63;
    const int lr   = lane & 15;
    const int lk   = lane >> 4;
    const int posb = l0 + wv*64 + lr;   // + mt*16

    // ---- prologue: h loads (reg-direct A layout), W2 -> holes, biases ----
    float h[4][8];
    if constexpr (FIRST){
        const float* hf = (const float*)hin;
        #pragma unroll
        for (int j = 0; j < 8; j++)
            #pragma unroll
            for (int mt = 0; mt < 4; mt++)
                h[mt][j] = hf[base + (size_t)(lk*8 + j)*L_ + posb + mt*16];
    } else {
        const f16_t* hh = (const f16_t*)hin;
        #pragma unroll
        for (int j = 0; j < 8; j++)
            #pragma unroll
            for (int mt = 0; mt < 4; mt++)
                h[mt][j] = (float)hh[base + (size_t)(lk*8 + j)*L_ + posb + mt*16];
    }

    // W2 -> hole-rows 128..255: W2[k*32+n] -> hole(n,k)
    for (int i = tid; i < 1024; i += 256){
        const int k = i >> 5, n = i & 31;
        AO[(size_t)(128 + n*4 + (k >> 3))*AST + 32 + (k & 7)] = (f16_t)W2[i];
    }
    float bias1[2], bias2[2];
    #pragma unroll
    for (int nt = 0; nt < 2; nt++){ bias1[nt] = b1[nt*16 + lr]; bias2[nt] = b2[nt*16 + lr]; }

    // ---- per-position softmax -> A-frags in registers (h dies here) ----
    f16x8 a[4];
    #pragma unroll
    for (int mt = 0; mt < 4; mt++){
        float mq = h[mt][0];
        #pragma unroll
        for (int j = 1; j < 8; j++) mq = fmaxf(mq, h[mt][j]);
        float es[8]; float qs = 0.f;
        #pragma unroll
        for (int j = 0; j < 8; j++){ es[j] = __expf(h[mt][j] - mq); qs += es[j]; }
        const float inv = __builtin_amdgcn_rcpf(qs);
        #pragma unroll
        for (int j = 0; j < 8; j++) a[mt][j] = (f16_t)(es[j] * inv);
    }

    // ---- merge: 4 segments per lane + shfl logsumexp combine over 8 q-lanes ----
    const int row = tid >> 3;        // c_in 0..31
    const int qq  = tid & 7;         // segment group / n-column group
    const int hdm = row >> 3, dm = row & 7;
    {
        const float* pp = part + (size_t)(b*H_ + hdm) * S_ * 80;
        float pm[4];
        #pragma unroll
        for (int t4 = 0; t4 < 4; t4++) pm[t4] = pp[(qq + 8*t4)*80 + dm];
        float M = fmaxf(fmaxf(pm[0], pm[1]), fmaxf(pm[2], pm[3]));
        float ss = 0.f;
        float kvr[8];
        #pragma unroll
        for (int e = 0; e < 8; e++) kvr[e] = 0.f;
        #pragma unroll
        for (int t4 = 0; t4 < 4; t4++){
            const int s = qq + 8*t4;
            const float sc = __expf(pm[t4] - M);
            ss = fmaf(pp[s*80 + 8 + dm], sc, ss);
            const f32x4 k0 = *(const f32x4*)&pp[s*80 + 16 + dm*8];
            const f32x4 k1 = *(const f32x4*)&pp[s*80 + 16 + dm*8 + 4];
            #pragma unroll
            for (int e = 0; e < 4; e++){
                kvr[e]   = fmaf(k0[e], sc, kvr[e]);
                kvr[4+e] = fmaf(k1[e], sc, kvr[4+e]);
            }
        }
        // combine across the 8 q-lanes (lane bits 0..2): logsumexp merge
        #pragma unroll
        for (int off = 1; off < 8; off <<= 1){
            const float Mo  = __shfl_xor(M, off);
            const float sso = __shfl_xor(ss, off);
            const float Mn  = fmaxf(M, Mo);
            const float sa  = __expf(M - Mn), sb = __expf(Mo - Mn);
            ss = ss*sa + sso*sb;
            #pragma unroll
            for (int e = 0; e < 8; e++){
                const float ko = __shfl_xor(kvr[e], off);
                kvr[e] = kvr[e]*sa + ko*sb;
            }
            M = Mn;
        }
        const float iss = 1.0f / ss;

        // W1eff[row][qq*4..+3] = sum_e kvn[row][e] * W1[hdm*8+e][qq*4..+3] -> holes 0..127
        f32x4 acc = {0.f, 0.f, 0.f, 0.f};
        #pragma unroll
        for (int e = 0; e < 8; e++){
            const f32x4 w = *(const f32x4*)&W1[(hdm*8 + e)*32 + qq*4];
            acc += kvr[e] * w;
        }
        #pragma unroll
        for (int j2 = 0; j2 < 4; j2++)
            AO[(size_t)((qq*4 + j2)*4 + hdm)*AST + 32 + dm] = (f16_t)(acc[j2] * iss);
    }
    __syncthreads();   // the ONLY barrier: W1eff + W2 holes visible

    // ---- MFMA FCs ----
    const f32x4 zero = {0.f, 0.f, 0.f, 0.f};
    f16x8 bw[2];
    f32x4 d[8];

    // FC1: A = P (registers), B = W1eff (holes 0..127)
    #pragma unroll
    for (int nt = 0; nt < 2; nt++)
        bw[nt] = *(const f16x8*)&AO[(size_t)((nt*16 + lr)*4 + lk)*AST + 32];
    #pragma unroll
    for (int nt = 0; nt < 2; nt++)
        #pragma unroll
        for (int mt = 0; mt < 4; mt++)
            d[nt*4+mt] = __builtin_amdgcn_mfma_f32_16x16x32_f16(a[mt], bw[nt], zero, 0, 0, 0);

    // bias + gelu + writeback as A2 into Ash rows (cols 0..31; wave-private rows)
    #pragma unroll
    for (int nt = 0; nt < 2; nt++){
        #pragma unroll
        for (int mt = 0; mt < 4; mt++)
            #pragma unroll
            for (int r = 0; r < 4; r++){
                const float v = gelu_f(d[nt*4+mt][r] + bias1[nt]);
                AO[(size_t)(wv*64 + mt*16 + lk*4 + r)*AST + (nt*16 + lr)] = (f16_t)v;
            }
    }

    // FC2: A2 from Ash rows, B = W2 (holes 128..255). Same-wave LDS write->read
    // ordering (R5-verified) -- no barrier.
    f16x8 a2[4];
    #pragma unroll
    for (int mt = 0; mt < 4; mt++)
        a2[mt] = *(const f16x8*)&AO[(size_t)(wv*64 + mt*16 + lr)*AST + lk*8];
    #pragma unroll
    for (int nt = 0; nt < 2; nt++)
        bw[nt] = *(const f16x8*)&AO[(size_t)(128 + (nt*16 + lr)*4 + lk)*AST + 32];
    #pragma unroll
    for (int nt = 0; nt < 2; nt++)
        #pragma unroll
        for (int mt = 0; mt < 4; mt++)
            d[nt*4+mt] = __builtin_amdgcn_mfma_f32_16x16x32_f16(a2[mt], bw[nt], zero, 0, 0, 0);

    // bias + gelu on D (fp32)
    #pragma unroll
    for (int nt = 0; nt < 2; nt++)
        #pragma unroll
        for (int mt = 0; mt < 4; mt++)
            #pragma unroll
            for (int r = 0; r < 4; r++)
                d[nt*4+mt][r] = gelu_f(d[nt*4+mt][r] + bias2[nt]);

    if (!LAST){
        // direct f16x4 store: lane owns 4 consecutive positions of channel nt*16+lr
        #pragma unroll
        for (int nt = 0; nt < 2; nt++)
            #pragma unroll
            for (int mt = 0; mt < 4; mt++){
                const f32x4 dv = d[nt*4+mt];
                f16x4 hv = { (f16_t)dv[0], (f16_t)dv[1], (f16_t)dv[2], (f16_t)dv[3] };
                *(f16x4*)&hout[base + (size_t)(nt*16 + lr)*L_
                               + l0 + wv*64 + mt*16 + lk*4] = hv;
            }
    } else {
        // channel sums: reduce over the 4 lk-lanes sharing lr, then global atomic
        #pragma unroll
        for (int nt = 0; nt < 2; nt++){
            float ps = 0.f;
            #pragma unroll
            for (int mt = 0; mt < 4; mt++)
                ps += d[nt*4+mt][0] + d[nt*4+mt][1] + d[nt*4+mt][2] + d[nt*4+mt][3];
            ps += __shfl_xor(ps, 16);
            ps += __shfl_xor(ps, 32);
            if (lk == 0) atomicAdd(&pooled[b*32 + nt*16 + lr], ps);
        }
    }
}

// ---- head: pooled/L -> Wh+bh -> BN(eval) -> gelu -> Wf+bf ----
__global__ __launch_bounds__(1024) void head_kernel(const float* __restrict__ pooled,
                                                    const float* __restrict__ Wh,
                                                    const float* __restrict__ bh,
                                                    const float* __restrict__ gam,
                                                    const float* __restrict__ bet,
                                                    const float* __restrict__ mean,
                                                    const float* __restrict__ var,
                                                    const float* __restrict__ Wf,
                                                    const float* __restrict__ bf,
                                                    float* __restrict__ out){
    __shared__ float y2[32][32];
    const int t = threadIdx.x;      // 0..1023
    const int b = t >> 5, c = t & 31;
    float a = bh[c];
    const float invL = 1.0f / (float)L_;
    #pragma unroll
    for (int d = 0; d < 32; d++) a += (pooled[b*32 + d] * invL) * Wh[d*32 + c];
    a = (a - mean[c]) * rsqrtf(var[c] + 1e-5f) * gam[c] + bet[c];
    y2[b][c] = gelu_f(a);
    __syncthreads();
    if (t < B_*DOUT_){
        const int b2 = t / DOUT_, j = t % DOUT_;
        float r = bf[j];
        #pragma unroll
        for (int c2 = 0; c2 < 32; c2++) r += y2[b2][c2] * Wf[c2*DOUT_ + j];
        out[t] = r;
    }
}

extern "C" void kernel_launch(void* const* d_in, const int* in_sizes, int n_in,
                              void* d_out, int out_size, void* d_ws, size_t ws_size,
                              hipStream_t stream){
    (void)in_sizes; (void)n_in; (void)out_size; (void)ws_size;
    const float* x    = (const float*)d_in[0];
    const float* fW1  = (const float*)d_in[1];
    const float* fb1  = (const float*)d_in[2];
    const float* fW2  = (const float*)d_in[3];
    const float* fb2  = (const float*)d_in[4];
    const float* Wh   = (const float*)d_in[5];
    const float* bh   = (const float*)d_in[6];
    const float* gam  = (const float*)d_in[7];
    const float* bet  = (const float*)d_in[8];
    const float* mean = (const float*)d_in[9];
    const float* var  = (const float*)d_in[10];
    const float* Wf   = (const float*)d_in[11];
    const float* bf   = (const float*)d_in[12];
    float* out = (float*)d_out;

    f16_t* hbuf   = (f16_t*)d_ws;                                  // B*C*L f16 (32 MB)
    float* part   = (float*)((char*)d_ws + (size_t)B_*C_*L_*2);    // B*H*S_*80 (~1.3 MB)
    float* pooled = part + (size_t)B_*H_*S_*80;                    // B*C

    dim3 sgrid(S_, H_, B_);
    dim3 bgrid(L_/TILE, B_);

    // 7 dispatches total.
    // block 0 (input = x f32, output -> hbuf f16)
    stats_kernel<float><<<sgrid, 256, 0, stream>>>(x, part, nullptr);
    block_kernel<true, false><<<bgrid, 256, 0, stream>>>(x, hbuf, part,
        fW1, fb1, fW2, fb2, nullptr);
    // block 1 (in-place on hbuf f16)
    stats_kernel<f16_t><<<sgrid, 256, 0, stream>>>(hbuf, part, nullptr);
    block_kernel<false, false><<<bgrid, 256, 0, stream>>>(hbuf, hbuf, part,
        fW1 + C_*C_, fb1 + C_, fW2 + C_*C_, fb2 + C_, nullptr);
    // block 2 (no h write; reduce into pooled; stats2 zeroes pooled)
    stats_kernel<f16_t><<<sgrid, 256, 0, stream>>>(hbuf, part, pooled);
    block_kernel<false, true><<<bgrid, 256, 0, stream>>>(hbuf, nullptr, part,
        fW1 + 2*C_*C_, fb1 + 2*C_, fW2 + 2*C_*C_, fb2 + 2*C_, pooled);

    head_kernel<<<1, 1024, 0, stream>>>(pooled, Wh, bh, gam, bet, mean, var, Wf, bf, out);
}